// Round 5
// baseline (251.667 us; speedup 1.0000x reference)
//
#include <hip/hip_runtime.h>
#include <math.h>

// Problem constants (from reference): S=7, NB=2, C=20
#define SS 7
#define CC 20
#define CELL_PRED 30            // C + NB*5
#define CELL_TGT  25            // C + 1 + 4
#define TILE 128                // cells per tile
#define BLOCK 128               // threads per block (2 waves)
#define P4_PER_TILE (TILE * CELL_PRED / 4)   // 960 float4 = 15 chunks of 64
#define T4_PER_TILE (TILE * CELL_TGT / 4)    // 800 float4 = 12.5 chunks of 64
#define GRID 1280               // 5 blocks/CU (LDS 28.2KB), persistent
// R4 lesson: with VGPR-staged copies the compiler (VGPR_Count=68) ping-pongs
// a few payload registers -> only ~2 loads in flight per wave -> 0.85-1.2 TB/s
// across ALL structures (R1/R2/R4 invariant). R3 hit 2 TB/s only because its
// spill loop was accidentally deep. Fix: global_load_lds DMA (zero payload
// VGPRs, all ~27 tile-loads in flight until the pre-barrier vmcnt(0) drain).

__device__ __forceinline__ void load_lds16(const float4* g, float4* l) {
    // 16B/lane global->LDS DMA. LDS dest = wave-uniform base + lane*16,
    // which matches our contiguous chunk layout exactly (no padding!).
    __builtin_amdgcn_global_load_lds(
        (const __attribute__((address_space(1))) void*)g,
        (__attribute__((address_space(3))) void*)l, 16, 0, 0);
}

__device__ __forceinline__ float iou_box(const float* __restrict__ a,
                                         const float* __restrict__ b) {
    const float EPS = 1e-6f;
    float ax1 = a[0] - a[2] * 0.5f, ay1 = a[1] - a[3] * 0.5f;
    float ax2 = a[0] + a[2] * 0.5f, ay2 = a[1] + a[3] * 0.5f;
    float bx1 = b[0] - b[2] * 0.5f, by1 = b[1] - b[3] * 0.5f;
    float bx2 = b[0] + b[2] * 0.5f, by2 = b[1] + b[3] * 0.5f;
    float iw = fmaxf(fminf(ax2, bx2) - fmaxf(ax1, bx1), 0.0f);
    float ih = fmaxf(fminf(ay2, by2) - fmaxf(ay1, by1), 0.0f);
    float inter = iw * ih;
    float area_a = fabsf((ax2 - ax1) * (ay2 - ay1));
    float area_b = fabsf((bx2 - bx1) * (by2 - by1));
    return inter / (area_a + area_b - inter + EPS);
}

__global__ __launch_bounds__(BLOCK) void yolo_loss_fused(
    const float* __restrict__ pred,   // [nCells * 30]
    const float* __restrict__ tgt,    // [nCells * 25]
    float* __restrict__ out,          // [1]
    double* __restrict__ accum,       // d_ws+0: double sum (memset 0)
    int* __restrict__ counter,        // d_ws+8: int arrival count (memset 0)
    int nTiles, double invN)
{
    __shared__ __align__(16) float s_pred[TILE * CELL_PRED]; // 15360 B
    __shared__ __align__(16) float s_tgt [TILE * CELL_TGT];  // 12800 B
    __shared__ float s_red[2];

    const int tid  = threadIdx.x;
    const int w    = tid >> 6;    // wave id: 0 or 1
    const int lane = tid & 63;
    float loss = 0.0f;

    for (int t = blockIdx.x; t < nTiles; t += GRID) {
        __syncthreads();   // previous tile's LDS reads complete before overwrite

        // ---- async DMA staging: global -> LDS, no payload VGPRs ----
        {
            const float4* gp = (const float4*)pred + (size_t)t * P4_PER_TILE;
            const float4* gt = (const float4*)tgt + (size_t)t * T4_PER_TILE;
            float4* sp = (float4*)s_pred;
            float4* st = (float4*)s_tgt;
            // pred: 15 full 64-f4 chunks, interleaved across the 2 waves
            #pragma unroll
            for (int c = w; c < 15; c += 2)
                load_lds16(gp + c * 64 + lane, sp + c * 64);
            // tgt: 12 full chunks ...
            #pragma unroll
            for (int c = w; c < 12; c += 2)
                load_lds16(gt + c * 64 + lane, st + c * 64);
            // ... + 32-f4 tail via plain load+ds_write (barrier drains it anyway)
            if (tid < 32) st[768 + tid] = gt[768 + tid];
        }
        __syncthreads();   // vmcnt(0) drain: all DMAs landed in LDS

        // ---- compute this tile: one cell per thread ----
        {
            const float* p  = s_pred + tid * CELL_PRED;
            const float* tt = s_tgt  + tid * CELL_TGT;
            const float* b1 = p + CC;
            const float* b2 = p + CC + 5;
            const float* tb = tt + CC;

            float obj = (tb[0] == 1.0f) ? 1.0f : 0.0f;

            float iou1 = iou_box(b1, tb);
            float iou2 = iou_box(b2, tb);
            bool pick1 = iou1 > iou2;
            float r0 = pick1 ? b1[0] : b2[0];
            float r1 = pick1 ? b1[1] : b2[1];
            float r2 = pick1 ? b1[2] : b2[2];
            float r3 = pick1 ? b1[3] : b2[3];
            float r4 = pick1 ? b1[4] : b2[4];

            float dx = r0 - tb[0], dy = r1 - tb[1];
            float xy = dx * dx + dy * dy;
            float dw = sqrtf(r2) - sqrtf(tb[2]);
            float dh = sqrtf(r3) - sqrtf(tb[3]);
            float wh = dw * dw + dh * dh;
            float coord = 5.0f * (xy + wh);
            float dconf = r4 - tb[4];
            float conf = dconf * dconf;

            float cls = 0.0f;
            #pragma unroll
            for (int k = 0; k < CC; ++k) {
                float d = p[k] - tt[k];
                cls += d * d;
            }

            float noobj = 0.5f * (1.0f - obj) * (b1[4] * b1[4] + b2[4] * b2[4]);
            loss += obj * (coord + conf + cls) + noobj;
        }
    }

    // ---- block reduction: wave butterfly, then 2 waves via LDS ----
    #pragma unroll
    for (int off = 32; off > 0; off >>= 1)
        loss += __shfl_down(loss, off, 64);
    __syncthreads();
    if ((tid & 63) == 0) s_red[tid >> 6] = loss;
    __syncthreads();

    // ---- fused final reduce: double atomic + last-block-done ----
    if (tid == 0) {
        double part = (double)s_red[0] + (double)s_red[1];
        atomicAdd(accum, part);
        __threadfence();             // sum visible before arrival
        int old = atomicAdd(counter, 1);
        if (old == GRID - 1) {
            double total = atomicAdd(accum, 0.0);  // device-scope atomic read
            out[0] = (float)(total * invN);
        }
    }
}

extern "C" void kernel_launch(void* const* d_in, const int* in_sizes, int n_in,
                              void* d_out, int out_size, void* d_ws, size_t ws_size,
                              hipStream_t stream) {
    const float* pred = (const float*)d_in[0];
    const float* tgt  = (const float*)d_in[1];
    float* out = (float*)d_out;
    double* accum = (double*)d_ws;
    int* counter = (int*)((char*)d_ws + 8);

    const int N = in_sizes[0] / (SS * SS * CELL_PRED);   // 16384
    const int nCells = N * SS * SS;                      // 802816 (divisible by TILE)
    const int nTiles = nCells / TILE;                    // 6272

    hipMemsetAsync(d_ws, 0, 16, stream);                 // zero accum + counter
    yolo_loss_fused<<<GRID, BLOCK, 0, stream>>>(
        pred, tgt, out, accum, counter, nTiles, 1.0 / (double)N);
}

// Round 6
// 198.322 us; speedup vs baseline: 1.2690x; 1.2690x over previous
//
#include <hip/hip_runtime.h>
#include <math.h>

// Problem constants (from reference): S=7, NB=2, C=20
#define SS 7
#define CC 20
#define CELL_PRED 30            // C + NB*5
#define CELL_TGT  25            // C + 1 + 4
#define BLOCK 256
#define GRID 1024               // 4 blocks/CU, persistent-ish; stride 262144 cells
// R5 lesson: every LDS-staged structure (VGPR or DMA) bursts ~14KB/wave then
// dies at a vmcnt(0)+barrier cliff -> device outstanding-bytes sawtooths to
// zero every tile -> 0.7-1.2 TB/s regardless of occupancy/staging style.
// This version has NO LDS staging, NO barriers in the hot path: each thread
// reads its own cell directly (wave = contiguous 14KB slab, L1/L2 coalesces
// the 120/100-byte strides), computes, and immediately issues the next burst.
// Tail: per-block partial + tiny 2nd kernel (R4/R5's 1280 serialized
// same-address double atomics are also under test by their removal).

__device__ __forceinline__ float cell_loss(const float* __restrict__ pred,
                                           const float* __restrict__ tgt,
                                           int c) {
    const float EPS = 1e-6f;
    // tgt: 25 scalar dword loads (100B stride -> only 4-aligned)
    const float* tp = tgt + (size_t)c * CELL_TGT;
    float tv[CELL_TGT];
    #pragma unroll
    for (int j = 0; j < CELL_TGT; ++j) tv[j] = tp[j];

    // pred: 15 float2 loads (120B stride -> always 8-aligned).
    // Class part (j<10) is consumed on the fly to cap live registers;
    // accumulation order matches the k=0..19 sequential sum of prior rounds.
    const float2* p2 = (const float2*)(pred + (size_t)c * CELL_PRED);
    float cls = 0.0f;
    #pragma unroll
    for (int j = 0; j < 10; ++j) {
        float2 v = p2[j];
        float d0 = v.x - tv[2 * j];
        float d1 = v.y - tv[2 * j + 1];
        cls += d0 * d0;
        cls += d1 * d1;
    }
    // boxes: pred words 20..29
    float b[10];
    #pragma unroll
    for (int j = 0; j < 5; ++j) {
        float2 v = p2[10 + j];
        b[2 * j] = v.x; b[2 * j + 1] = v.y;
    }
    const float* b1 = b;        // pred[20..24]
    const float* b2 = b + 5;    // pred[25..29]
    const float* tb = tv + CC;  // tgt[20..24]

    float obj = (tb[0] == 1.0f) ? 1.0f : 0.0f;

    // IoU(b1,tb) and IoU(b2,tb), midpoint format
    float t_x1 = tb[0] - tb[2] * 0.5f, t_y1 = tb[1] - tb[3] * 0.5f;
    float t_x2 = tb[0] + tb[2] * 0.5f, t_y2 = tb[1] + tb[3] * 0.5f;
    float t_area = fabsf((t_x2 - t_x1) * (t_y2 - t_y1));

    float a_x1 = b1[0] - b1[2] * 0.5f, a_y1 = b1[1] - b1[3] * 0.5f;
    float a_x2 = b1[0] + b1[2] * 0.5f, a_y2 = b1[1] + b1[3] * 0.5f;
    float iw1 = fmaxf(fminf(a_x2, t_x2) - fmaxf(a_x1, t_x1), 0.0f);
    float ih1 = fmaxf(fminf(a_y2, t_y2) - fmaxf(a_y1, t_y1), 0.0f);
    float inter1 = iw1 * ih1;
    float area1 = fabsf((a_x2 - a_x1) * (a_y2 - a_y1));
    float iou1 = inter1 / (area1 + t_area - inter1 + EPS);

    float c_x1 = b2[0] - b2[2] * 0.5f, c_y1 = b2[1] - b2[3] * 0.5f;
    float c_x2 = b2[0] + b2[2] * 0.5f, c_y2 = b2[1] + b2[3] * 0.5f;
    float iw2 = fmaxf(fminf(c_x2, t_x2) - fmaxf(c_x1, t_x1), 0.0f);
    float ih2 = fmaxf(fminf(c_y2, t_y2) - fmaxf(c_y1, t_y1), 0.0f);
    float inter2 = iw2 * ih2;
    float area2 = fabsf((c_x2 - c_x1) * (c_y2 - c_y1));
    float iou2 = inter2 / (area2 + t_area - inter2 + EPS);

    bool pick1 = iou1 > iou2;
    float r0 = pick1 ? b1[0] : b2[0];
    float r1 = pick1 ? b1[1] : b2[1];
    float r2 = pick1 ? b1[2] : b2[2];
    float r3 = pick1 ? b1[3] : b2[3];
    float r4 = pick1 ? b1[4] : b2[4];

    float dx = r0 - tb[0], dy = r1 - tb[1];
    float xy = dx * dx + dy * dy;
    float dw = sqrtf(r2) - sqrtf(tb[2]);
    float dh = sqrtf(r3) - sqrtf(tb[3]);
    float wh = dw * dw + dh * dh;
    float coord = 5.0f * (xy + wh);
    float dconf = r4 - tb[4];
    float conf = dconf * dconf;

    float noobj = 0.5f * (1.0f - obj) * (b1[4] * b1[4] + b2[4] * b2[4]);
    return obj * (coord + conf + cls) + noobj;
}

__global__ __launch_bounds__(BLOCK) void yolo_stream(
    const float* __restrict__ pred,
    const float* __restrict__ tgt,
    float* __restrict__ partials,     // [GRID]
    int nCells, int fullIters)
{
    const int tid = threadIdx.x;
    int c = blockIdx.x * BLOCK + tid;
    const int stride = GRID * BLOCK;  // 262144

    float loss = 0.0f;
    for (int it = 0; it < fullIters; ++it, c += stride)
        loss += cell_loss(pred, tgt, c);
    if (c < nCells)                    // ragged tail (g < nCells % stride)
        loss += cell_loss(pred, tgt, c);

    // wave butterfly, then 4 waves via tiny LDS
    #pragma unroll
    for (int off = 32; off > 0; off >>= 1)
        loss += __shfl_down(loss, off, 64);
    __shared__ float s_red[4];
    if ((tid & 63) == 0) s_red[tid >> 6] = loss;
    __syncthreads();
    if (tid == 0)
        partials[blockIdx.x] = (s_red[0] + s_red[1]) + (s_red[2] + s_red[3]);
}

__global__ __launch_bounds__(BLOCK) void yolo_final_reduce(
    const float* __restrict__ partials, int nPartials, double invN,
    float* __restrict__ out)
{
    __shared__ double s_red[4];
    const float4* p4 = (const float4*)partials;   // d_ws is 16-aligned
    double sum = 0.0;
    for (int i = threadIdx.x; i < (nPartials >> 2); i += BLOCK) {
        float4 v = p4[i];
        sum += (double)v.x + (double)v.y + (double)v.z + (double)v.w;
    }
    for (int i = ((nPartials >> 2) << 2) + threadIdx.x; i < nPartials; i += BLOCK)
        sum += (double)partials[i];
    #pragma unroll
    for (int off = 32; off > 0; off >>= 1)
        sum += __shfl_down(sum, off, 64);
    if ((threadIdx.x & 63) == 0) s_red[threadIdx.x >> 6] = sum;
    __syncthreads();
    if (threadIdx.x == 0) {
        double s = (s_red[0] + s_red[1]) + (s_red[2] + s_red[3]);
        out[0] = (float)(s * invN);
    }
}

extern "C" void kernel_launch(void* const* d_in, const int* in_sizes, int n_in,
                              void* d_out, int out_size, void* d_ws, size_t ws_size,
                              hipStream_t stream) {
    const float* pred = (const float*)d_in[0];
    const float* tgt  = (const float*)d_in[1];
    float* out = (float*)d_out;
    float* partials = (float*)d_ws;

    const int N = in_sizes[0] / (SS * SS * CELL_PRED);   // 16384
    const int nCells = N * SS * SS;                      // 802816
    const int stride = GRID * BLOCK;                     // 262144
    const int fullIters = nCells / stride;               // 3

    yolo_stream<<<GRID, BLOCK, 0, stream>>>(pred, tgt, partials, nCells, fullIters);
    yolo_final_reduce<<<1, BLOCK, 0, stream>>>(partials, GRID, 1.0 / (double)N, out);
}